// Round 1
// baseline (4355.523 us; speedup 1.0000x reference)
//
#include <hip/hip_runtime.h>

// GCN: 3x GCNConv (34->4->4->2) + linear (2->4), N=500K nodes, E=8M edges.
// Factorization: gcn(h)[d] = dinv[d]*(sum_{s->d} g[s] + g[d]) + b,
//                g[s] = dinv[s]*(h[s]@W).
// Workspace layout (floats): deg/dinv [N] | g [4N] | acc [4N]  (~18 MB).

#define BLK 256

__global__ void count_deg_kernel(const int* __restrict__ dst,
                                 float* __restrict__ deg, int E4, int rem) {
    int t = blockIdx.x * blockDim.x + threadIdx.x;
    if (t < E4) {
        int4 d = ((const int4*)dst)[t];
        atomicAdd(&deg[d.x], 1.0f);
        atomicAdd(&deg[d.y], 1.0f);
        atomicAdd(&deg[d.z], 1.0f);
        atomicAdd(&deg[d.w], 1.0f);
    } else if (t - E4 < rem) {
        atomicAdd(&deg[dst[4 * E4 + (t - E4)]], 1.0f);
    }
}

__global__ void make_dinv_kernel(float* __restrict__ deg, int N) {
    int i = blockIdx.x * blockDim.x + threadIdx.x;
    if (i < N) deg[i] = rsqrtf(deg[i] + 1.0f);  // +1 = self loop
}

// layer 1: g[i] = dinv[i] * (x[i] @ W1); acc[i] = g[i] (self-loop init)
__global__ void transform1_kernel(const float* __restrict__ x,
                                  const float* __restrict__ W1,
                                  const float* __restrict__ dinv,
                                  float* __restrict__ g,
                                  float* __restrict__ acc, int N) {
    __shared__ float sW[136];
    if (threadIdx.x < 136) sW[threadIdx.x] = W1[threadIdx.x];
    __syncthreads();
    int i = blockIdx.x * blockDim.x + threadIdx.x;
    if (i >= N) return;
    const float2* xr = (const float2*)(x + (size_t)i * 34);  // 136B stride, 8B aligned
    float o0 = 0.f, o1 = 0.f, o2 = 0.f, o3 = 0.f;
#pragma unroll
    for (int k = 0; k < 17; ++k) {
        float2 v = xr[k];
        o0 = fmaf(v.x, sW[(2 * k) * 4 + 0], o0);
        o1 = fmaf(v.x, sW[(2 * k) * 4 + 1], o1);
        o2 = fmaf(v.x, sW[(2 * k) * 4 + 2], o2);
        o3 = fmaf(v.x, sW[(2 * k) * 4 + 3], o3);
        o0 = fmaf(v.y, sW[(2 * k + 1) * 4 + 0], o0);
        o1 = fmaf(v.y, sW[(2 * k + 1) * 4 + 1], o1);
        o2 = fmaf(v.y, sW[(2 * k + 1) * 4 + 2], o2);
        o3 = fmaf(v.y, sW[(2 * k + 1) * 4 + 3], o3);
    }
    float dv = dinv[i];
    float4 gv = make_float4(o0 * dv, o1 * dv, o2 * dv, o3 * dv);
    ((float4*)g)[i] = gv;
    ((float4*)acc)[i] = gv;
}

// per edge: acc[dst] += g[src]  (F live channels, stride-4 layout)
template <int F>
__global__ void scatter_kernel(const int* __restrict__ src,
                               const int* __restrict__ dst,
                               const float* __restrict__ g,
                               float* __restrict__ acc, int E4, int rem) {
    int t = blockIdx.x * blockDim.x + threadIdx.x;
    if (t < E4) {
        int4 s4 = ((const int4*)src)[t];
        int4 d4 = ((const int4*)dst)[t];
        int ss[4] = {s4.x, s4.y, s4.z, s4.w};
        int dd[4] = {d4.x, d4.y, d4.z, d4.w};
#pragma unroll
        for (int e = 0; e < 4; ++e) {
            const float* gp = g + (size_t)ss[e] * 4;
            float* ap = acc + (size_t)dd[e] * 4;
            if (F == 4) {
                float4 gv = *(const float4*)gp;
                atomicAdd(ap + 0, gv.x);
                atomicAdd(ap + 1, gv.y);
                atomicAdd(ap + 2, gv.z);
                atomicAdd(ap + 3, gv.w);
            } else {
                float2 gv = *(const float2*)gp;
                atomicAdd(ap + 0, gv.x);
                atomicAdd(ap + 1, gv.y);
            }
        }
    } else if (t - E4 < rem) {
        int e = 4 * E4 + (t - E4);
        int s = src[e], d = dst[e];
        const float* gp = g + (size_t)s * 4;
        float* ap = acc + (size_t)d * 4;
#pragma unroll
        for (int f = 0; f < F; ++f) atomicAdd(ap + f, gp[f]);
    }
}

// h = relu(dinv*acc + b_prev); g = acc = dinv*(h @ W_next). FIN fixed at 4.
template <int FOUT>
__global__ void finish_transform_kernel(const float* __restrict__ dinv,
                                        const float* __restrict__ b,
                                        const float* __restrict__ W,
                                        float* __restrict__ g,
                                        float* __restrict__ acc, int N) {
    __shared__ float sW[4 * FOUT];
    __shared__ float sb[4];
    if (threadIdx.x < 4 * FOUT) sW[threadIdx.x] = W[threadIdx.x];
    if (threadIdx.x < 4) sb[threadIdx.x] = b[threadIdx.x];
    __syncthreads();
    int i = blockIdx.x * blockDim.x + threadIdx.x;
    if (i >= N) return;
    float dv = dinv[i];
    float4 a = ((const float4*)acc)[i];
    float h0 = fmaxf(fmaf(a.x, dv, sb[0]), 0.f);
    float h1 = fmaxf(fmaf(a.y, dv, sb[1]), 0.f);
    float h2 = fmaxf(fmaf(a.z, dv, sb[2]), 0.f);
    float h3 = fmaxf(fmaf(a.w, dv, sb[3]), 0.f);
    if (FOUT == 4) {
        float4 o;
        o.x = dv * (h0 * sW[0] + h1 * sW[4] + h2 * sW[8] + h3 * sW[12]);
        o.y = dv * (h0 * sW[1] + h1 * sW[5] + h2 * sW[9] + h3 * sW[13]);
        o.z = dv * (h0 * sW[2] + h1 * sW[6] + h2 * sW[10] + h3 * sW[14]);
        o.w = dv * (h0 * sW[3] + h1 * sW[7] + h2 * sW[11] + h3 * sW[15]);
        ((float4*)g)[i] = o;
        ((float4*)acc)[i] = o;
    } else {  // FOUT == 2, keep stride-4 layout (channels 0,1 live)
        float2 o;
        o.x = dv * (h0 * sW[0] + h1 * sW[2] + h2 * sW[4] + h3 * sW[6]);
        o.y = dv * (h0 * sW[1] + h1 * sW[3] + h2 * sW[5] + h3 * sW[7]);
        *(float2*)(g + (size_t)i * 4) = o;
        *(float2*)(acc + (size_t)i * 4) = o;
    }
}

// h3 = relu(dinv*acc + b3); out = h3@Wl + bl; d_out = [out (4N) | h3 (2N)]
__global__ void final_kernel(const float* __restrict__ dinv,
                             const float* __restrict__ b3,
                             const float* __restrict__ Wl,
                             const float* __restrict__ bl,
                             const float* __restrict__ acc,
                             float* __restrict__ out, int N) {
    __shared__ float sW[8];
    __shared__ float sbl[4];
    __shared__ float sb3[2];
    if (threadIdx.x < 8) sW[threadIdx.x] = Wl[threadIdx.x];
    if (threadIdx.x < 4) sbl[threadIdx.x] = bl[threadIdx.x];
    if (threadIdx.x < 2) sb3[threadIdx.x] = b3[threadIdx.x];
    __syncthreads();
    int i = blockIdx.x * blockDim.x + threadIdx.x;
    if (i >= N) return;
    float dv = dinv[i];
    const float* ap = acc + (size_t)i * 4;
    float h0 = fmaxf(fmaf(ap[0], dv, sb3[0]), 0.f);
    float h1 = fmaxf(fmaf(ap[1], dv, sb3[1]), 0.f);
    float4 o;
    o.x = fmaf(h0, sW[0], fmaf(h1, sW[4], sbl[0]));
    o.y = fmaf(h0, sW[1], fmaf(h1, sW[5], sbl[1]));
    o.z = fmaf(h0, sW[2], fmaf(h1, sW[6], sbl[2]));
    o.w = fmaf(h0, sW[3], fmaf(h1, sW[7], sbl[3]));
    ((float4*)out)[i] = o;
    ((float2*)(out + (size_t)4 * N))[i] = make_float2(h0, h1);
}

extern "C" void kernel_launch(void* const* d_in, const int* in_sizes, int n_in,
                              void* d_out, int out_size, void* d_ws, size_t ws_size,
                              hipStream_t stream) {
    const float* x  = (const float*)d_in[0];
    const int*   ei = (const int*)d_in[1];
    const float* W1 = (const float*)d_in[2];
    const float* b1 = (const float*)d_in[3];
    const float* W2 = (const float*)d_in[4];
    const float* b2 = (const float*)d_in[5];
    const float* W3 = (const float*)d_in[6];
    const float* b3 = (const float*)d_in[7];
    const float* Wl = (const float*)d_in[8];
    const float* bl = (const float*)d_in[9];
    float* out = (float*)d_out;

    const int N = in_sizes[0] / 34;
    const int E = in_sizes[1] / 2;
    const int* src = ei;
    const int* dst = ei + E;

    float* deg = (float*)d_ws;                         // N floats (deg then dinv)
    float* g   = deg + (((size_t)N + 3) & ~(size_t)3); // 4N floats
    float* acc = g + (size_t)4 * N;                    // 4N floats

    const int E4 = E >> 2, rem = E & 3;
    const int nb_edge = (E4 + rem + BLK - 1) / BLK;
    const int nb_node = (N + BLK - 1) / BLK;

    hipMemsetAsync(deg, 0, (size_t)N * sizeof(float), stream);
    count_deg_kernel<<<nb_edge, BLK, 0, stream>>>(dst, deg, E4, rem);
    make_dinv_kernel<<<nb_node, BLK, 0, stream>>>(deg, N);
    transform1_kernel<<<nb_node, BLK, 0, stream>>>(x, W1, deg, g, acc, N);
    scatter_kernel<4><<<nb_edge, BLK, 0, stream>>>(src, dst, g, acc, E4, rem);
    finish_transform_kernel<4><<<nb_node, BLK, 0, stream>>>(deg, b1, W2, g, acc, N);
    scatter_kernel<4><<<nb_edge, BLK, 0, stream>>>(src, dst, g, acc, E4, rem);
    finish_transform_kernel<2><<<nb_node, BLK, 0, stream>>>(deg, b2, W3, g, acc, N);
    scatter_kernel<2><<<nb_edge, BLK, 0, stream>>>(src, dst, g, acc, E4, rem);
    final_kernel<<<nb_node, BLK, 0, stream>>>(deg, b3, Wl, bl, acc, out, N);
}

// Round 2
// 1362.823 us; speedup vs baseline: 3.1960x; 3.1960x over previous
//
#include <hip/hip_runtime.h>

// GCN: 3x GCNConv (34->4->4->2) + linear (2->4), N=500K nodes, E=8M edges.
// Round 2: replace 3x atomic-scatter (88M fp32 atomics, 1GB write-through each)
// with one counting-sort into dst-grouped CSR + 3x atomic-free fused
// gather-aggregate passes.
// gcn(h)[d] = dinv[d]*(sum_{s->d} g[s] + g[d]) + b,  g[s] = dinv[s]*(h[s]@W).
//
// ws layout: cnt[N] int | bsum[NB] int | dinv[N] f32 | esrc[E] int |
//            g1[4N] f32 | g2[4N] f32   (g3 aliases g1, float2 stride)

#define BLK 256

__device__ __forceinline__ float4 add4(float4 a, float4 b) {
    return make_float4(a.x + b.x, a.y + b.y, a.z + b.z, a.w + b.w);
}

__global__ void hist_kernel(const int* __restrict__ dst, int* __restrict__ cnt,
                            int E4, int rem) {
    int t = blockIdx.x * blockDim.x + threadIdx.x;
    if (t < E4) {
        int4 d = ((const int4*)dst)[t];
        atomicAdd(&cnt[d.x], 1);
        atomicAdd(&cnt[d.y], 1);
        atomicAdd(&cnt[d.z], 1);
        atomicAdd(&cnt[d.w], 1);
    } else if (t - E4 < rem) {
        atomicAdd(&cnt[dst[4 * E4 + (t - E4)]], 1);
    }
}

__global__ void dinv_kernel(const int* __restrict__ cnt, float* __restrict__ dinv, int N) {
    int i = blockIdx.x * blockDim.x + threadIdx.x;
    if (i < N) dinv[i] = rsqrtf((float)cnt[i] + 1.0f);  // +1 = self loop
}

// per-block sum of 256 counts
__global__ void scan_block_reduce(const int* __restrict__ cnt, int* __restrict__ bsum, int N) {
    __shared__ int sh[BLK];
    int t = threadIdx.x;
    int i = blockIdx.x * BLK + t;
    sh[t] = (i < N) ? cnt[i] : 0;
    __syncthreads();
    for (int off = BLK / 2; off > 0; off >>= 1) {
        if (t < off) sh[t] += sh[t + off];
        __syncthreads();
    }
    if (t == 0) bsum[blockIdx.x] = sh[0];
}

// single-block exclusive scan of block sums (nb ~ 2000)
__global__ void scan_bsums(int* __restrict__ bsum, int nb) {
    __shared__ int tmp[BLK];
    __shared__ int carry;
    int t = threadIdx.x;
    if (t == 0) carry = 0;
    __syncthreads();
    for (int base = 0; base < nb; base += BLK) {
        int v = (base + t < nb) ? bsum[base + t] : 0;
        tmp[t] = v;
        __syncthreads();
        for (int off = 1; off < BLK; off <<= 1) {
            int add = (t >= off) ? tmp[t - off] : 0;
            __syncthreads();
            tmp[t] += add;
            __syncthreads();
        }
        int incl = tmp[t];
        int excl = incl - v + carry;
        if (base + t < nb) bsum[base + t] = excl;
        __syncthreads();
        if (t == BLK - 1) carry += incl;
        __syncthreads();
    }
}

// per-block exclusive scan + block offset -> cnt becomes start offsets
__global__ void scan_apply(int* __restrict__ cnt, const int* __restrict__ bsum, int N) {
    __shared__ int tmp[BLK];
    int t = threadIdx.x;
    int i = blockIdx.x * BLK + t;
    int v = (i < N) ? cnt[i] : 0;
    tmp[t] = v;
    __syncthreads();
    for (int off = 1; off < BLK; off <<= 1) {
        int add = (t >= off) ? tmp[t - off] : 0;
        __syncthreads();
        tmp[t] += add;
        __syncthreads();
    }
    if (i < N) cnt[i] = tmp[t] - v + bsum[blockIdx.x];
}

// counting-sort scatter: esrc grouped by dst; cnt ends as segment END offsets
__global__ void sort_kernel(const int* __restrict__ src, const int* __restrict__ dst,
                            int* __restrict__ cnt, int* __restrict__ esrc,
                            int E4, int rem) {
    int t = blockIdx.x * blockDim.x + threadIdx.x;
    if (t < E4) {
        int4 s4 = ((const int4*)src)[t];
        int4 d4 = ((const int4*)dst)[t];
        int p0 = atomicAdd(&cnt[d4.x], 1);
        int p1 = atomicAdd(&cnt[d4.y], 1);
        int p2 = atomicAdd(&cnt[d4.z], 1);
        int p3 = atomicAdd(&cnt[d4.w], 1);
        esrc[p0] = s4.x;
        esrc[p1] = s4.y;
        esrc[p2] = s4.z;
        esrc[p3] = s4.w;
    } else if (t - E4 < rem) {
        int e = 4 * E4 + (t - E4);
        int p = atomicAdd(&cnt[dst[e]], 1);
        esrc[p] = src[e];
    }
}

// layer 1 transform: g1[i] = dinv[i] * (x[i] @ W1)
__global__ void transform1_kernel(const float* __restrict__ x,
                                  const float* __restrict__ W1,
                                  const float* __restrict__ dinv,
                                  float* __restrict__ g1, int N) {
    __shared__ float sW[136];
    if (threadIdx.x < 136) sW[threadIdx.x] = W1[threadIdx.x];
    __syncthreads();
    int i = blockIdx.x * blockDim.x + threadIdx.x;
    if (i >= N) return;
    const float2* xr = (const float2*)(x + (size_t)i * 34);  // 136B stride, 8B aligned
    float o0 = 0.f, o1 = 0.f, o2 = 0.f, o3 = 0.f;
#pragma unroll
    for (int k = 0; k < 17; ++k) {
        float2 v = xr[k];
        o0 = fmaf(v.x, sW[(2 * k) * 4 + 0], o0);
        o1 = fmaf(v.x, sW[(2 * k) * 4 + 1], o1);
        o2 = fmaf(v.x, sW[(2 * k) * 4 + 2], o2);
        o3 = fmaf(v.x, sW[(2 * k) * 4 + 3], o3);
        o0 = fmaf(v.y, sW[(2 * k + 1) * 4 + 0], o0);
        o1 = fmaf(v.y, sW[(2 * k + 1) * 4 + 1], o1);
        o2 = fmaf(v.y, sW[(2 * k + 1) * 4 + 2], o2);
        o3 = fmaf(v.y, sW[(2 * k + 1) * 4 + 3], o3);
    }
    float dv = dinv[i];
    ((float4*)g1)[i] = make_float4(o0 * dv, o1 * dv, o2 * dv, o3 * dv);
}

// agg over g1 (float4) + finish layer1 + transform by W2 -> g2 (float4)
__global__ void agg12_kernel(const int* __restrict__ cnt, const int* __restrict__ esrc,
                             const float* __restrict__ g1, const float* __restrict__ dinv,
                             const float* __restrict__ b1, const float* __restrict__ W2,
                             float* __restrict__ g2, int N) {
    int i = blockIdx.x * blockDim.x + threadIdx.x;
    if (i >= N) return;
    int start = (i == 0) ? 0 : cnt[i - 1];
    int end = cnt[i];
    const float4* g = (const float4*)g1;
    float4 a0 = g[i];  // self loop
    float4 a1 = make_float4(0, 0, 0, 0), a2 = a1, a3 = a1;
    int p = start;
    for (; p + 4 <= end; p += 4) {
        int s0 = esrc[p], s1 = esrc[p + 1], s2 = esrc[p + 2], s3 = esrc[p + 3];
        a0 = add4(a0, g[s0]);
        a1 = add4(a1, g[s1]);
        a2 = add4(a2, g[s2]);
        a3 = add4(a3, g[s3]);
    }
    for (; p < end; ++p) a0 = add4(a0, g[esrc[p]]);
    float4 s = add4(add4(a0, a1), add4(a2, a3));
    float dv = dinv[i];
    float h0 = fmaxf(fmaf(s.x, dv, b1[0]), 0.f);
    float h1 = fmaxf(fmaf(s.y, dv, b1[1]), 0.f);
    float h2 = fmaxf(fmaf(s.z, dv, b1[2]), 0.f);
    float h3 = fmaxf(fmaf(s.w, dv, b1[3]), 0.f);
    float4 o;
    o.x = dv * (h0 * W2[0] + h1 * W2[4] + h2 * W2[8] + h3 * W2[12]);
    o.y = dv * (h0 * W2[1] + h1 * W2[5] + h2 * W2[9] + h3 * W2[13]);
    o.z = dv * (h0 * W2[2] + h1 * W2[6] + h2 * W2[10] + h3 * W2[14]);
    o.w = dv * (h0 * W2[3] + h1 * W2[7] + h2 * W2[11] + h3 * W2[15]);
    ((float4*)g2)[i] = o;
}

// agg over g2 (float4) + finish layer2 + transform by W3 -> g3 (float2, stride 2)
__global__ void agg23_kernel(const int* __restrict__ cnt, const int* __restrict__ esrc,
                             const float* __restrict__ g2, const float* __restrict__ dinv,
                             const float* __restrict__ b2, const float* __restrict__ W3,
                             float* __restrict__ g3, int N) {
    int i = blockIdx.x * blockDim.x + threadIdx.x;
    if (i >= N) return;
    int start = (i == 0) ? 0 : cnt[i - 1];
    int end = cnt[i];
    const float4* g = (const float4*)g2;
    float4 a0 = g[i];
    float4 a1 = make_float4(0, 0, 0, 0), a2 = a1, a3 = a1;
    int p = start;
    for (; p + 4 <= end; p += 4) {
        int s0 = esrc[p], s1 = esrc[p + 1], s2 = esrc[p + 2], s3 = esrc[p + 3];
        a0 = add4(a0, g[s0]);
        a1 = add4(a1, g[s1]);
        a2 = add4(a2, g[s2]);
        a3 = add4(a3, g[s3]);
    }
    for (; p < end; ++p) a0 = add4(a0, g[esrc[p]]);
    float4 s = add4(add4(a0, a1), add4(a2, a3));
    float dv = dinv[i];
    float h0 = fmaxf(fmaf(s.x, dv, b2[0]), 0.f);
    float h1 = fmaxf(fmaf(s.y, dv, b2[1]), 0.f);
    float h2 = fmaxf(fmaf(s.z, dv, b2[2]), 0.f);
    float h3 = fmaxf(fmaf(s.w, dv, b2[3]), 0.f);
    float2 o;
    o.x = dv * (h0 * W3[0] + h1 * W3[2] + h2 * W3[4] + h3 * W3[6]);
    o.y = dv * (h0 * W3[1] + h1 * W3[3] + h2 * W3[5] + h3 * W3[7]);
    ((float2*)g3)[i] = o;
}

// agg over g3 (float2) + finish layer3 + linear -> d_out = [out 4N | h3 2N]
__global__ void agg3f_kernel(const int* __restrict__ cnt, const int* __restrict__ esrc,
                             const float* __restrict__ g3, const float* __restrict__ dinv,
                             const float* __restrict__ b3, const float* __restrict__ Wl,
                             const float* __restrict__ bl, float* __restrict__ out, int N) {
    int i = blockIdx.x * blockDim.x + threadIdx.x;
    if (i >= N) return;
    int start = (i == 0) ? 0 : cnt[i - 1];
    int end = cnt[i];
    const float2* g = (const float2*)g3;
    float2 q = g[i];
    float ax0 = q.x, ay0 = q.y, ax1 = 0.f, ay1 = 0.f, ax2 = 0.f, ay2 = 0.f, ax3 = 0.f, ay3 = 0.f;
    int p = start;
    for (; p + 4 <= end; p += 4) {
        int s0 = esrc[p], s1 = esrc[p + 1], s2 = esrc[p + 2], s3 = esrc[p + 3];
        float2 v0 = g[s0], v1 = g[s1], v2 = g[s2], v3 = g[s3];
        ax0 += v0.x; ay0 += v0.y;
        ax1 += v1.x; ay1 += v1.y;
        ax2 += v2.x; ay2 += v2.y;
        ax3 += v3.x; ay3 += v3.y;
    }
    for (; p < end; ++p) { float2 v = g[esrc[p]]; ax0 += v.x; ay0 += v.y; }
    float sx = (ax0 + ax1) + (ax2 + ax3);
    float sy = (ay0 + ay1) + (ay2 + ay3);
    float dv = dinv[i];
    float h0 = fmaxf(fmaf(sx, dv, b3[0]), 0.f);
    float h1 = fmaxf(fmaf(sy, dv, b3[1]), 0.f);
    float4 o;
    o.x = fmaf(h0, Wl[0], fmaf(h1, Wl[4], bl[0]));
    o.y = fmaf(h0, Wl[1], fmaf(h1, Wl[5], bl[1]));
    o.z = fmaf(h0, Wl[2], fmaf(h1, Wl[6], bl[2]));
    o.w = fmaf(h0, Wl[3], fmaf(h1, Wl[7], bl[3]));
    ((float4*)out)[i] = o;
    ((float2*)(out + (size_t)4 * N))[i] = make_float2(h0, h1);
}

extern "C" void kernel_launch(void* const* d_in, const int* in_sizes, int n_in,
                              void* d_out, int out_size, void* d_ws, size_t ws_size,
                              hipStream_t stream) {
    const float* x  = (const float*)d_in[0];
    const int*   ei = (const int*)d_in[1];
    const float* W1 = (const float*)d_in[2];
    const float* b1 = (const float*)d_in[3];
    const float* W2 = (const float*)d_in[4];
    const float* b2 = (const float*)d_in[5];
    const float* W3 = (const float*)d_in[6];
    const float* b3 = (const float*)d_in[7];
    const float* Wl = (const float*)d_in[8];
    const float* bl = (const float*)d_in[9];
    float* out = (float*)d_out;

    const int N = in_sizes[0] / 34;
    const int E = in_sizes[1] / 2;
    const int* src = ei;
    const int* dst = ei + E;
    const int NB = (N + BLK - 1) / BLK;

    auto al16 = [](size_t v) { return (v + 15) & ~(size_t)15; };
    char* w = (char*)d_ws;
    size_t off = 0;
    int*   cnt  = (int*)(w + off);   off += al16((size_t)N * 4);
    int*   bsum = (int*)(w + off);   off += al16((size_t)NB * 4);
    float* dinv = (float*)(w + off); off += al16((size_t)N * 4);
    int*   esrc = (int*)(w + off);   off += al16((size_t)E * 4);
    float* g1   = (float*)(w + off); off += al16((size_t)4 * N * 4);
    float* g2   = (float*)(w + off);
    float* g3   = g1;  // layer-1 g dead by the time g3 is written

    const int E4 = E >> 2, rem = E & 3;
    const int nb_edge = (E4 + rem + BLK - 1) / BLK;
    const int nb_node = NB;

    hipMemsetAsync(cnt, 0, (size_t)N * sizeof(int), stream);
    hist_kernel<<<nb_edge, BLK, 0, stream>>>(dst, cnt, E4, rem);
    dinv_kernel<<<nb_node, BLK, 0, stream>>>(cnt, dinv, N);
    scan_block_reduce<<<NB, BLK, 0, stream>>>(cnt, bsum, N);
    scan_bsums<<<1, BLK, 0, stream>>>(bsum, NB);
    scan_apply<<<NB, BLK, 0, stream>>>(cnt, bsum, N);
    sort_kernel<<<nb_edge, BLK, 0, stream>>>(src, dst, cnt, esrc, E4, rem);
    transform1_kernel<<<nb_node, BLK, 0, stream>>>(x, W1, dinv, g1, N);
    agg12_kernel<<<nb_node, BLK, 0, stream>>>(cnt, esrc, g1, dinv, b1, W2, g2, N);
    agg23_kernel<<<nb_node, BLK, 0, stream>>>(cnt, esrc, g2, dinv, b2, W3, g3, N);
    agg3f_kernel<<<nb_node, BLK, 0, stream>>>(cnt, esrc, g3, dinv, b3, Wl, bl, out, N);
}

// Round 3
// 621.234 us; speedup vs baseline: 7.0111x; 2.1937x over previous
//
#include <hip/hip_runtime.h>

// GCN: 3x GCNConv (34->4->4->2) + linear (2->4), N=500K nodes, E=8M edges.
// Round 3: coarse bucketing (512 nodes/bucket) + per-bucket LDS aggregation.
// Kills the counting-sort's 500MB write-amplification (random 4B writes) and
// all large random global atomic passes.
// gcn(h)[d] = dinv[d]*(sum_{s->d} g[s] + g[d]) + b,  g[s] = dinv[s]*(h[s]@W).
//
// ws: bsize_pad[NBUK*16] | gcur_pad[NBUK*16] | bstart[NBUK+1] | dinv[N] |
//     ep[E] u32 (packed dst_local<<23 | src) | g1[4N] | g2[4N]  (g3 = g1)

#define BLK 256
#define BUCKET_BITS 9
#define BUCKET (1 << BUCKET_BITS)   // 512 nodes per bucket
#define MAXBUK 1024
#define CHUNK 16384                 // edges per binning block
#define PAD 16                      // counter padding: 64B apart

// --- kernel 1: bucket sizes (per-block LDS hist -> padded global merge) ---
__global__ void bsize_kernel(const int* __restrict__ dst, int* __restrict__ bsize,
                             int E, int nbuk) {
    __shared__ int hist[MAXBUK];
    int t = threadIdx.x;
    for (int b = t; b < nbuk; b += BLK) hist[b] = 0;
    __syncthreads();
    int e0 = blockIdx.x * CHUNK;
    int e1 = min(e0 + CHUNK, E);
    for (int e = e0 + t; e < e1; e += BLK)
        atomicAdd(&hist[dst[e] >> BUCKET_BITS], 1);
    __syncthreads();
    for (int b = t; b < nbuk; b += BLK)
        if (hist[b]) atomicAdd(&bsize[b * PAD], hist[b]);
}

// --- kernel 2: single-block exclusive scan over bucket sizes ---
__global__ void scan_kernel(const int* __restrict__ bsize, int* __restrict__ bstart,
                            int* __restrict__ gcur, int nbuk) {
    __shared__ int tmp[BLK];
    __shared__ int carry;
    int t = threadIdx.x;
    if (t == 0) carry = 0;
    __syncthreads();
    for (int base = 0; base < nbuk; base += BLK) {
        int i = base + t;
        int v = (i < nbuk) ? bsize[i * PAD] : 0;
        tmp[t] = v;
        __syncthreads();
        for (int off = 1; off < BLK; off <<= 1) {
            int add = (t >= off) ? tmp[t - off] : 0;
            __syncthreads();
            tmp[t] += add;
            __syncthreads();
        }
        int excl = tmp[t] - v + carry;
        if (i < nbuk) { bstart[i] = excl; gcur[i * PAD] = excl; }
        __syncthreads();
        if (t == BLK - 1) carry += tmp[t];
        __syncthreads();
    }
    if (t == 0) bstart[nbuk] = carry;
}

// --- kernel 3: binning scatter; ep = (dst_local << 23) | src ---
__global__ void bin_kernel(const int* __restrict__ src, const int* __restrict__ dst,
                           int* __restrict__ gcur, unsigned* __restrict__ ep,
                           int E, int nbuk) {
    __shared__ int hist[MAXBUK];
    __shared__ int base[MAXBUK];
    int t = threadIdx.x;
    for (int b = t; b < nbuk; b += BLK) hist[b] = 0;
    __syncthreads();
    int e0 = blockIdx.x * CHUNK;
    int e1 = min(e0 + CHUNK, E);
    for (int e = e0 + t; e < e1; e += BLK)
        atomicAdd(&hist[dst[e] >> BUCKET_BITS], 1);
    __syncthreads();
    for (int b = t; b < nbuk; b += BLK) {
        int c = hist[b];
        base[b] = c ? atomicAdd(&gcur[b * PAD], c) : 0;
        hist[b] = 0;
    }
    __syncthreads();
    for (int e = e0 + t; e < e1; e += BLK) {
        int d = dst[e];
        int bk = d >> BUCKET_BITS;
        int r = atomicAdd(&hist[bk], 1);
        ep[base[bk] + r] = ((unsigned)(d & (BUCKET - 1)) << 23) | (unsigned)src[e];
    }
}

// --- kernel 4: per-bucket degree -> dinv ---
__global__ void dinv_kernel(const unsigned* __restrict__ ep, const int* __restrict__ bstart,
                            float* __restrict__ dinv, int N) {
    __shared__ int cnt[BUCKET];
    int t = threadIdx.x, b = blockIdx.x;
    for (int l = t; l < BUCKET; l += BLK) cnt[l] = 0;
    __syncthreads();
    int s = bstart[b], e = bstart[b + 1];
    for (int p = s + t; p < e; p += BLK)
        atomicAdd(&cnt[ep[p] >> 23], 1);
    __syncthreads();
    int gbase = b << BUCKET_BITS;
    for (int l = t; l < BUCKET; l += BLK)
        if (gbase + l < N) dinv[gbase + l] = rsqrtf((float)cnt[l] + 1.0f);
}

// --- kernel 5: g1[i] = dinv[i] * (x[i] @ W1) ---
__global__ void transform1_kernel(const float* __restrict__ x,
                                  const float* __restrict__ W1,
                                  const float* __restrict__ dinv,
                                  float* __restrict__ g1, int N) {
    __shared__ float sW[136];
    if (threadIdx.x < 136) sW[threadIdx.x] = W1[threadIdx.x];
    __syncthreads();
    int i = blockIdx.x * blockDim.x + threadIdx.x;
    if (i >= N) return;
    const float2* xr = (const float2*)(x + (size_t)i * 34);
    float o0 = 0.f, o1 = 0.f, o2 = 0.f, o3 = 0.f;
#pragma unroll
    for (int k = 0; k < 17; ++k) {
        float2 v = xr[k];
        o0 = fmaf(v.x, sW[(2 * k) * 4 + 0], o0);
        o1 = fmaf(v.x, sW[(2 * k) * 4 + 1], o1);
        o2 = fmaf(v.x, sW[(2 * k) * 4 + 2], o2);
        o3 = fmaf(v.x, sW[(2 * k) * 4 + 3], o3);
        o0 = fmaf(v.y, sW[(2 * k + 1) * 4 + 0], o0);
        o1 = fmaf(v.y, sW[(2 * k + 1) * 4 + 1], o1);
        o2 = fmaf(v.y, sW[(2 * k + 1) * 4 + 2], o2);
        o3 = fmaf(v.y, sW[(2 * k + 1) * 4 + 3], o3);
    }
    float dv = dinv[i];
    ((float4*)g1)[i] = make_float4(o0 * dv, o1 * dv, o2 * dv, o3 * dv);
}

// --- kernel 6: agg over g1 + finish layer1 + W2 -> g2 (float4) ---
__global__ void agg12_kernel(const unsigned* __restrict__ ep, const int* __restrict__ bstart,
                             const float* __restrict__ g1, const float* __restrict__ dinv,
                             const float* __restrict__ b1, const float* __restrict__ W2,
                             float* __restrict__ g2, int N) {
    __shared__ float acc[BUCKET * 4];
    int t = threadIdx.x, b = blockIdx.x;
    int gbase = b << BUCKET_BITS;
    int nn = min(BUCKET, N - gbase);
    const float4* g = (const float4*)g1;
    for (int l = t; l < nn; l += BLK) {
        float4 v = g[gbase + l];  // self loop
        acc[l * 4 + 0] = v.x; acc[l * 4 + 1] = v.y;
        acc[l * 4 + 2] = v.z; acc[l * 4 + 3] = v.w;
    }
    __syncthreads();
    int s = bstart[b], e = bstart[b + 1];
    for (int p = s + t; p < e; p += BLK) {
        unsigned pe = ep[p];
        float4 v = g[pe & 0x7FFFFFu];
        float* a = &acc[(pe >> 23) * 4];
        atomicAdd(a + 0, v.x); atomicAdd(a + 1, v.y);
        atomicAdd(a + 2, v.z); atomicAdd(a + 3, v.w);
    }
    __syncthreads();
    for (int l = t; l < nn; l += BLK) {
        float dv = dinv[gbase + l];
        float h0 = fmaxf(fmaf(acc[l * 4 + 0], dv, b1[0]), 0.f);
        float h1 = fmaxf(fmaf(acc[l * 4 + 1], dv, b1[1]), 0.f);
        float h2 = fmaxf(fmaf(acc[l * 4 + 2], dv, b1[2]), 0.f);
        float h3 = fmaxf(fmaf(acc[l * 4 + 3], dv, b1[3]), 0.f);
        float4 o;
        o.x = dv * (h0 * W2[0] + h1 * W2[4] + h2 * W2[8] + h3 * W2[12]);
        o.y = dv * (h0 * W2[1] + h1 * W2[5] + h2 * W2[9] + h3 * W2[13]);
        o.z = dv * (h0 * W2[2] + h1 * W2[6] + h2 * W2[10] + h3 * W2[14]);
        o.w = dv * (h0 * W2[3] + h1 * W2[7] + h2 * W2[11] + h3 * W2[15]);
        ((float4*)g2)[gbase + l] = o;
    }
}

// --- kernel 7: agg over g2 + finish layer2 + W3 -> g3 (float2) ---
__global__ void agg23_kernel(const unsigned* __restrict__ ep, const int* __restrict__ bstart,
                             const float* __restrict__ g2, const float* __restrict__ dinv,
                             const float* __restrict__ b2, const float* __restrict__ W3,
                             float* __restrict__ g3, int N) {
    __shared__ float acc[BUCKET * 4];
    int t = threadIdx.x, b = blockIdx.x;
    int gbase = b << BUCKET_BITS;
    int nn = min(BUCKET, N - gbase);
    const float4* g = (const float4*)g2;
    for (int l = t; l < nn; l += BLK) {
        float4 v = g[gbase + l];
        acc[l * 4 + 0] = v.x; acc[l * 4 + 1] = v.y;
        acc[l * 4 + 2] = v.z; acc[l * 4 + 3] = v.w;
    }
    __syncthreads();
    int s = bstart[b], e = bstart[b + 1];
    for (int p = s + t; p < e; p += BLK) {
        unsigned pe = ep[p];
        float4 v = g[pe & 0x7FFFFFu];
        float* a = &acc[(pe >> 23) * 4];
        atomicAdd(a + 0, v.x); atomicAdd(a + 1, v.y);
        atomicAdd(a + 2, v.z); atomicAdd(a + 3, v.w);
    }
    __syncthreads();
    for (int l = t; l < nn; l += BLK) {
        float dv = dinv[gbase + l];
        float h0 = fmaxf(fmaf(acc[l * 4 + 0], dv, b2[0]), 0.f);
        float h1 = fmaxf(fmaf(acc[l * 4 + 1], dv, b2[1]), 0.f);
        float h2 = fmaxf(fmaf(acc[l * 4 + 2], dv, b2[2]), 0.f);
        float h3 = fmaxf(fmaf(acc[l * 4 + 3], dv, b2[3]), 0.f);
        float2 o;
        o.x = dv * (h0 * W3[0] + h1 * W3[2] + h2 * W3[4] + h3 * W3[6]);
        o.y = dv * (h0 * W3[1] + h1 * W3[3] + h2 * W3[5] + h3 * W3[7]);
        ((float2*)g3)[gbase + l] = o;
    }
}

// --- kernel 8: agg over g3 (float2) + finish layer3 + linear -> out ---
__global__ void agg3f_kernel(const unsigned* __restrict__ ep, const int* __restrict__ bstart,
                             const float* __restrict__ g3, const float* __restrict__ dinv,
                             const float* __restrict__ b3, const float* __restrict__ Wl,
                             const float* __restrict__ bl, float* __restrict__ out, int N) {
    __shared__ float acc[BUCKET * 2];
    int t = threadIdx.x, b = blockIdx.x;
    int gbase = b << BUCKET_BITS;
    int nn = min(BUCKET, N - gbase);
    const float2* g = (const float2*)g3;
    for (int l = t; l < nn; l += BLK) {
        float2 v = g[gbase + l];
        acc[l * 2 + 0] = v.x; acc[l * 2 + 1] = v.y;
    }
    __syncthreads();
    int s = bstart[b], e = bstart[b + 1];
    for (int p = s + t; p < e; p += BLK) {
        unsigned pe = ep[p];
        float2 v = g[pe & 0x7FFFFFu];
        float* a = &acc[(pe >> 23) * 2];
        atomicAdd(a + 0, v.x); atomicAdd(a + 1, v.y);
    }
    __syncthreads();
    for (int l = t; l < nn; l += BLK) {
        float dv = dinv[gbase + l];
        float h0 = fmaxf(fmaf(acc[l * 2 + 0], dv, b3[0]), 0.f);
        float h1 = fmaxf(fmaf(acc[l * 2 + 1], dv, b3[1]), 0.f);
        float4 o;
        o.x = fmaf(h0, Wl[0], fmaf(h1, Wl[4], bl[0]));
        o.y = fmaf(h0, Wl[1], fmaf(h1, Wl[5], bl[1]));
        o.z = fmaf(h0, Wl[2], fmaf(h1, Wl[6], bl[2]));
        o.w = fmaf(h0, Wl[3], fmaf(h1, Wl[7], bl[3]));
        ((float4*)out)[gbase + l] = o;
        ((float2*)(out + (size_t)4 * N))[gbase + l] = make_float2(h0, h1);
    }
}

extern "C" void kernel_launch(void* const* d_in, const int* in_sizes, int n_in,
                              void* d_out, int out_size, void* d_ws, size_t ws_size,
                              hipStream_t stream) {
    const float* x  = (const float*)d_in[0];
    const int*   ei = (const int*)d_in[1];
    const float* W1 = (const float*)d_in[2];
    const float* b1 = (const float*)d_in[3];
    const float* W2 = (const float*)d_in[4];
    const float* b2 = (const float*)d_in[5];
    const float* W3 = (const float*)d_in[6];
    const float* b3 = (const float*)d_in[7];
    const float* Wl = (const float*)d_in[8];
    const float* bl = (const float*)d_in[9];
    float* out = (float*)d_out;

    const int N = in_sizes[0] / 34;
    const int E = in_sizes[1] / 2;
    const int* src = ei;
    const int* dst = ei + E;
    const int NBUK = (N + BUCKET - 1) >> BUCKET_BITS;

    auto al16 = [](size_t v) { return (v + 15) & ~(size_t)15; };
    char* w = (char*)d_ws;
    size_t off = 0;
    int*      bsize  = (int*)(w + off);      off += al16((size_t)NBUK * PAD * 4);
    int*      gcur   = (int*)(w + off);      off += al16((size_t)NBUK * PAD * 4);
    int*      bstart = (int*)(w + off);      off += al16((size_t)(NBUK + 1) * 4);
    float*    dinv   = (float*)(w + off);    off += al16((size_t)N * 4);
    unsigned* ep     = (unsigned*)(w + off); off += al16((size_t)E * 4);
    float*    g1     = (float*)(w + off);    off += al16((size_t)4 * N * 4);
    float*    g2     = (float*)(w + off);
    float*    g3     = g1;  // g1 dead once g3 is written

    const int nbin = (E + CHUNK - 1) / CHUNK;
    const int nb_node = (N + BLK - 1) / BLK;

    hipMemsetAsync(bsize, 0, (size_t)NBUK * PAD * 4, stream);
    bsize_kernel<<<nbin, BLK, 0, stream>>>(dst, bsize, E, NBUK);
    scan_kernel<<<1, BLK, 0, stream>>>(bsize, bstart, gcur, NBUK);
    bin_kernel<<<nbin, BLK, 0, stream>>>(src, dst, gcur, ep, E, NBUK);
    dinv_kernel<<<NBUK, BLK, 0, stream>>>(ep, bstart, dinv, N);
    transform1_kernel<<<nb_node, BLK, 0, stream>>>(x, W1, dinv, g1, N);
    agg12_kernel<<<NBUK, BLK, 0, stream>>>(ep, bstart, g1, dinv, b1, W2, g2, N);
    agg23_kernel<<<NBUK, BLK, 0, stream>>>(ep, bstart, g2, dinv, b2, W3, g3, N);
    agg3f_kernel<<<NBUK, BLK, 0, stream>>>(ep, bstart, g3, dinv, b3, Wl, bl, out, N);
}

// Round 4
// 573.350 us; speedup vs baseline: 7.5966x; 1.0835x over previous
//
#include <hip/hip_runtime.h>

// GCN: 3x GCNConv (34->4->4->2) + linear (2->4), N=500K nodes, E=8M edges.
// Round 4: (a) LDS-staged binning -> coalesced run writes (fixes 7x write
// amplification), (b) transposed agg accumulators (kills structural 8-way
// LDS bank conflict), (c) BLK=512 aggs for ~95% wave occupancy, (d) fused
// dinv+transform1.
// gcn(h)[d] = dinv[d]*(sum_{s->d} g[s] + g[d]) + b,  g[s] = dinv[s]*(h[s]@W).
//
// ws: bsize_pad[NBUK*16] | gcur_pad[NBUK*16] | bstart[NBUK+1] | dinv[N] |
//     ep[E] u32 (packed dst_local<<23 | src) | g1[4N] | g2[4N]  (g3 = g1)

#define MAXBUK 1024
#define BUCKET_BITS 9
#define BUCKET 512
#define PAD 16

#define BS_BLK 256
#define BS_CHUNK 8192

#define BIN_BLK 512
#define BIN_CHUNK 16384

#define AGG_BLK 512
#define SC_BLK 256

// --- kernel 1: bucket sizes (per-block LDS hist -> padded global merge) ---
__global__ void bsize_kernel(const int* __restrict__ dst, int* __restrict__ bsize,
                             int E, int nbuk) {
    __shared__ int hist[MAXBUK];
    int t = threadIdx.x;
    for (int b = t; b < nbuk; b += BS_BLK) hist[b] = 0;
    __syncthreads();
    int e0 = blockIdx.x * BS_CHUNK;
    int e1 = min(e0 + BS_CHUNK, E);
    int cn = e1 - e0;
    const int4* dv = (const int4*)(dst + e0);  // e0 % 4 == 0, base 16B-aligned
    int n4 = cn >> 2;
    for (int i = t; i < n4; i += BS_BLK) {
        int4 d = dv[i];
        atomicAdd(&hist[d.x >> BUCKET_BITS], 1);
        atomicAdd(&hist[d.y >> BUCKET_BITS], 1);
        atomicAdd(&hist[d.z >> BUCKET_BITS], 1);
        atomicAdd(&hist[d.w >> BUCKET_BITS], 1);
    }
    for (int e = (n4 << 2) + t; e < cn; e += BS_BLK)
        atomicAdd(&hist[dst[e0 + e] >> BUCKET_BITS], 1);
    __syncthreads();
    for (int b = t; b < nbuk; b += BS_BLK)
        if (hist[b]) atomicAdd(&bsize[b * PAD], hist[b]);
}

// --- kernel 2: single-block exclusive scan over bucket sizes ---
__global__ void scan_kernel(const int* __restrict__ bsize, int* __restrict__ bstart,
                            int* __restrict__ gcur, int nbuk) {
    __shared__ int tmp[SC_BLK];
    __shared__ int carry;
    int t = threadIdx.x;
    if (t == 0) carry = 0;
    __syncthreads();
    for (int base = 0; base < nbuk; base += SC_BLK) {
        int i = base + t;
        int v = (i < nbuk) ? bsize[i * PAD] : 0;
        tmp[t] = v;
        __syncthreads();
        for (int off = 1; off < SC_BLK; off <<= 1) {
            int add = (t >= off) ? tmp[t - off] : 0;
            __syncthreads();
            tmp[t] += add;
            __syncthreads();
        }
        int excl = tmp[t] - v + carry;
        if (i < nbuk) { bstart[i] = excl; gcur[i * PAD] = excl; }
        __syncthreads();
        if (t == SC_BLK - 1) carry += tmp[t];
        __syncthreads();
    }
    if (t == 0) bstart[nbuk] = carry;
}

// --- kernel 3: LDS-staged binning; ep = (dst_local << 23) | src ---
__global__ void __launch_bounds__(BIN_BLK, 1)
bin_kernel(const int* __restrict__ src, const int* __restrict__ dst,
           int* __restrict__ gcur, unsigned* __restrict__ ep, int E, int nbuk) {
    __shared__ int hist[MAXBUK];       // counts, then rank cursor
    __shared__ int lbase[MAXBUK + 1];  // block-local exclusive scan
    __shared__ int gb[MAXBUK];         // reserved global base per bucket
    __shared__ int stmp[BIN_BLK];
    __shared__ int scarry;
    __shared__ unsigned stage[BIN_CHUNK];
    int t = threadIdx.x;
    for (int b = t; b < nbuk; b += BIN_BLK) hist[b] = 0;
    if (t == 0) scarry = 0;
    __syncthreads();
    int e0 = blockIdx.x * BIN_CHUNK;
    int e1 = min(e0 + BIN_CHUNK, E);
    int cn = e1 - e0;
    const int4* dv = (const int4*)(dst + e0);
    const int4* sv = (const int4*)(src + e0);
    int n4 = cn >> 2;
    // phase A: histogram
    for (int i = t; i < n4; i += BIN_BLK) {
        int4 d = dv[i];
        atomicAdd(&hist[d.x >> BUCKET_BITS], 1);
        atomicAdd(&hist[d.y >> BUCKET_BITS], 1);
        atomicAdd(&hist[d.z >> BUCKET_BITS], 1);
        atomicAdd(&hist[d.w >> BUCKET_BITS], 1);
    }
    for (int e = (n4 << 2) + t; e < cn; e += BIN_BLK)
        atomicAdd(&hist[dst[e0 + e] >> BUCKET_BITS], 1);
    __syncthreads();
    // phase B: block-local exclusive scan hist -> lbase
    for (int base = 0; base < nbuk; base += BIN_BLK) {
        int i = base + t;
        int v = (i < nbuk) ? hist[i] : 0;
        stmp[t] = v;
        __syncthreads();
        for (int off = 1; off < BIN_BLK; off <<= 1) {
            int add = (t >= off) ? stmp[t - off] : 0;
            __syncthreads();
            stmp[t] += add;
            __syncthreads();
        }
        if (i < nbuk) lbase[i] = stmp[t] - v + scarry;
        __syncthreads();
        if (t == BIN_BLK - 1) scarry += stmp[t];
        __syncthreads();
    }
    if (t == 0) lbase[nbuk] = scarry;  // == cn
    // reserve global ranges; reset hist as rank cursor
    for (int b = t; b < nbuk; b += BIN_BLK) {
        int c = hist[b];
        gb[b] = c ? atomicAdd(&gcur[b * PAD], c) : 0;
        hist[b] = 0;
    }
    __syncthreads();
    // phase C: rank + stage (sorted by bucket within the chunk)
    for (int i = t; i < n4; i += BIN_BLK) {
        int4 d = dv[i];
        int4 s = sv[i];
        int bk, r;
        bk = d.x >> BUCKET_BITS; r = atomicAdd(&hist[bk], 1);
        stage[lbase[bk] + r] = ((unsigned)(d.x & (BUCKET - 1)) << 23) | (unsigned)s.x;
        bk = d.y >> BUCKET_BITS; r = atomicAdd(&hist[bk], 1);
        stage[lbase[bk] + r] = ((unsigned)(d.y & (BUCKET - 1)) << 23) | (unsigned)s.y;
        bk = d.z >> BUCKET_BITS; r = atomicAdd(&hist[bk], 1);
        stage[lbase[bk] + r] = ((unsigned)(d.z & (BUCKET - 1)) << 23) | (unsigned)s.z;
        bk = d.w >> BUCKET_BITS; r = atomicAdd(&hist[bk], 1);
        stage[lbase[bk] + r] = ((unsigned)(d.w & (BUCKET - 1)) << 23) | (unsigned)s.w;
    }
    for (int e = (n4 << 2) + t; e < cn; e += BIN_BLK) {
        int d = dst[e0 + e];
        int bk = d >> BUCKET_BITS;
        int r = atomicAdd(&hist[bk], 1);
        stage[lbase[bk] + r] = ((unsigned)(d & (BUCKET - 1)) << 23) | (unsigned)src[e0 + e];
    }
    __syncthreads();
    // phase D: per-bucket coalesced run copy, one warp per bucket (strided)
    int wid = t >> 6, lane = t & 63;
    for (int b = wid; b < nbuk; b += (BIN_BLK >> 6)) {
        int lo = lbase[b];
        int c = lbase[b + 1] - lo;
        unsigned* dp = ep + gb[b];
        for (int j = lane; j < c; j += 64) dp[j] = stage[lo + j];
    }
}

// --- kernel 4: fused per-bucket degree->dinv + layer-1 transform ---
__global__ void dtf1_kernel(const unsigned* __restrict__ ep, const int* __restrict__ bstart,
                            const float* __restrict__ x, const float* __restrict__ W1,
                            float* __restrict__ dinv, float* __restrict__ g1, int N) {
    __shared__ int cnt[BUCKET];
    __shared__ float sW[136];
    int t = threadIdx.x, b = blockIdx.x;
    if (t < 136) sW[t] = W1[t];
    if (t < BUCKET) cnt[t] = 0;
    __syncthreads();
    int s = bstart[b], e = bstart[b + 1];
    for (int p = s + t; p < e; p += AGG_BLK)
        atomicAdd(&cnt[ep[p] >> 23], 1);
    __syncthreads();
    int gbase = b << BUCKET_BITS;
    int i = gbase + t;
    if (t < BUCKET && i < N) {
        float dv = rsqrtf((float)cnt[t] + 1.0f);
        dinv[i] = dv;
        const float2* xr = (const float2*)(x + (size_t)i * 34);
        float o0 = 0.f, o1 = 0.f, o2 = 0.f, o3 = 0.f;
#pragma unroll
        for (int k = 0; k < 17; ++k) {
            float2 v = xr[k];
            o0 = fmaf(v.x, sW[(2 * k) * 4 + 0], o0);
            o1 = fmaf(v.x, sW[(2 * k) * 4 + 1], o1);
            o2 = fmaf(v.x, sW[(2 * k) * 4 + 2], o2);
            o3 = fmaf(v.x, sW[(2 * k) * 4 + 3], o3);
            o0 = fmaf(v.y, sW[(2 * k + 1) * 4 + 0], o0);
            o1 = fmaf(v.y, sW[(2 * k + 1) * 4 + 1], o1);
            o2 = fmaf(v.y, sW[(2 * k + 1) * 4 + 2], o2);
            o3 = fmaf(v.y, sW[(2 * k + 1) * 4 + 3], o3);
        }
        ((float4*)g1)[i] = make_float4(o0 * dv, o1 * dv, o2 * dv, o3 * dv);
    }
}

// --- kernel 5: agg over g1 + finish layer1 + W2 -> g2 (float4) ---
__global__ void agg12_kernel(const unsigned* __restrict__ ep, const int* __restrict__ bstart,
                             const float* __restrict__ g1, const float* __restrict__ dinv,
                             const float* __restrict__ b1, const float* __restrict__ W2,
                             float* __restrict__ g2, int N) {
    __shared__ float acc[4][BUCKET];  // transposed: bank = l % 32 (all 32 banks)
    int t = threadIdx.x, b = blockIdx.x;
    int gbase = b << BUCKET_BITS;
    int nn = min(BUCKET, N - gbase);
    const float4* g = (const float4*)g1;
    if (t < nn) {
        float4 v = g[gbase + t];  // self loop
        acc[0][t] = v.x; acc[1][t] = v.y; acc[2][t] = v.z; acc[3][t] = v.w;
    }
    __syncthreads();
    int s = bstart[b], e = bstart[b + 1];
    for (int p = s + t; p < e; p += AGG_BLK) {
        unsigned pe = ep[p];
        float4 v = g[pe & 0x7FFFFFu];
        int l = pe >> 23;
        atomicAdd(&acc[0][l], v.x);
        atomicAdd(&acc[1][l], v.y);
        atomicAdd(&acc[2][l], v.z);
        atomicAdd(&acc[3][l], v.w);
    }
    __syncthreads();
    if (t < nn) {
        float dv = dinv[gbase + t];
        float h0 = fmaxf(fmaf(acc[0][t], dv, b1[0]), 0.f);
        float h1 = fmaxf(fmaf(acc[1][t], dv, b1[1]), 0.f);
        float h2 = fmaxf(fmaf(acc[2][t], dv, b1[2]), 0.f);
        float h3 = fmaxf(fmaf(acc[3][t], dv, b1[3]), 0.f);
        float4 o;
        o.x = dv * (h0 * W2[0] + h1 * W2[4] + h2 * W2[8] + h3 * W2[12]);
        o.y = dv * (h0 * W2[1] + h1 * W2[5] + h2 * W2[9] + h3 * W2[13]);
        o.z = dv * (h0 * W2[2] + h1 * W2[6] + h2 * W2[10] + h3 * W2[14]);
        o.w = dv * (h0 * W2[3] + h1 * W2[7] + h2 * W2[11] + h3 * W2[15]);
        ((float4*)g2)[gbase + t] = o;
    }
}

// --- kernel 6: agg over g2 + finish layer2 + W3 -> g3 (float2) ---
__global__ void agg23_kernel(const unsigned* __restrict__ ep, const int* __restrict__ bstart,
                             const float* __restrict__ g2, const float* __restrict__ dinv,
                             const float* __restrict__ b2, const float* __restrict__ W3,
                             float* __restrict__ g3, int N) {
    __shared__ float acc[4][BUCKET];
    int t = threadIdx.x, b = blockIdx.x;
    int gbase = b << BUCKET_BITS;
    int nn = min(BUCKET, N - gbase);
    const float4* g = (const float4*)g2;
    if (t < nn) {
        float4 v = g[gbase + t];
        acc[0][t] = v.x; acc[1][t] = v.y; acc[2][t] = v.z; acc[3][t] = v.w;
    }
    __syncthreads();
    int s = bstart[b], e = bstart[b + 1];
    for (int p = s + t; p < e; p += AGG_BLK) {
        unsigned pe = ep[p];
        float4 v = g[pe & 0x7FFFFFu];
        int l = pe >> 23;
        atomicAdd(&acc[0][l], v.x);
        atomicAdd(&acc[1][l], v.y);
        atomicAdd(&acc[2][l], v.z);
        atomicAdd(&acc[3][l], v.w);
    }
    __syncthreads();
    if (t < nn) {
        float dv = dinv[gbase + t];
        float h0 = fmaxf(fmaf(acc[0][t], dv, b2[0]), 0.f);
        float h1 = fmaxf(fmaf(acc[1][t], dv, b2[1]), 0.f);
        float h2 = fmaxf(fmaf(acc[2][t], dv, b2[2]), 0.f);
        float h3 = fmaxf(fmaf(acc[3][t], dv, b2[3]), 0.f);
        float2 o;
        o.x = dv * (h0 * W3[0] + h1 * W3[2] + h2 * W3[4] + h3 * W3[6]);
        o.y = dv * (h0 * W3[1] + h1 * W3[3] + h2 * W3[5] + h3 * W3[7]);
        ((float2*)g3)[gbase + t] = o;
    }
}

// --- kernel 7: agg over g3 (float2) + finish layer3 + linear -> out ---
__global__ void agg3f_kernel(const unsigned* __restrict__ ep, const int* __restrict__ bstart,
                             const float* __restrict__ g3, const float* __restrict__ dinv,
                             const float* __restrict__ b3, const float* __restrict__ Wl,
                             const float* __restrict__ bl, float* __restrict__ out, int N) {
    __shared__ float acc[2][BUCKET];
    int t = threadIdx.x, b = blockIdx.x;
    int gbase = b << BUCKET_BITS;
    int nn = min(BUCKET, N - gbase);
    const float2* g = (const float2*)g3;
    if (t < nn) {
        float2 v = g[gbase + t];
        acc[0][t] = v.x; acc[1][t] = v.y;
    }
    __syncthreads();
    int s = bstart[b], e = bstart[b + 1];
    for (int p = s + t; p < e; p += AGG_BLK) {
        unsigned pe = ep[p];
        float2 v = g[pe & 0x7FFFFFu];
        int l = pe >> 23;
        atomicAdd(&acc[0][l], v.x);
        atomicAdd(&acc[1][l], v.y);
    }
    __syncthreads();
    if (t < nn) {
        float dv = dinv[gbase + t];
        float h0 = fmaxf(fmaf(acc[0][t], dv, b3[0]), 0.f);
        float h1 = fmaxf(fmaf(acc[1][t], dv, b3[1]), 0.f);
        float4 o;
        o.x = fmaf(h0, Wl[0], fmaf(h1, Wl[4], bl[0]));
        o.y = fmaf(h0, Wl[1], fmaf(h1, Wl[5], bl[1]));
        o.z = fmaf(h0, Wl[2], fmaf(h1, Wl[6], bl[2]));
        o.w = fmaf(h0, Wl[3], fmaf(h1, Wl[7], bl[3]));
        ((float4*)out)[gbase + t] = o;
        ((float2*)(out + (size_t)4 * N))[gbase + t] = make_float2(h0, h1);
    }
}

extern "C" void kernel_launch(void* const* d_in, const int* in_sizes, int n_in,
                              void* d_out, int out_size, void* d_ws, size_t ws_size,
                              hipStream_t stream) {
    const float* x  = (const float*)d_in[0];
    const int*   ei = (const int*)d_in[1];
    const float* W1 = (const float*)d_in[2];
    const float* b1 = (const float*)d_in[3];
    const float* W2 = (const float*)d_in[4];
    const float* b2 = (const float*)d_in[5];
    const float* W3 = (const float*)d_in[6];
    const float* b3 = (const float*)d_in[7];
    const float* Wl = (const float*)d_in[8];
    const float* bl = (const float*)d_in[9];
    float* out = (float*)d_out;

    const int N = in_sizes[0] / 34;
    const int E = in_sizes[1] / 2;
    const int* src = ei;
    const int* dst = ei + E;
    const int NBUK = (N + BUCKET - 1) >> BUCKET_BITS;

    auto al16 = [](size_t v) { return (v + 15) & ~(size_t)15; };
    char* w = (char*)d_ws;
    size_t off = 0;
    int*      bsize  = (int*)(w + off);      off += al16((size_t)NBUK * PAD * 4);
    int*      gcur   = (int*)(w + off);      off += al16((size_t)NBUK * PAD * 4);
    int*      bstart = (int*)(w + off);      off += al16((size_t)(NBUK + 1) * 4);
    float*    dinv   = (float*)(w + off);    off += al16((size_t)N * 4);
    unsigned* ep     = (unsigned*)(w + off); off += al16((size_t)E * 4);
    float*    g1     = (float*)(w + off);    off += al16((size_t)4 * N * 4);
    float*    g2     = (float*)(w + off);
    float*    g3     = g1;  // g1 dead once g3 is written

    const int nb_bs  = (E + BS_CHUNK - 1) / BS_CHUNK;
    const int nb_bin = (E + BIN_CHUNK - 1) / BIN_CHUNK;

    hipMemsetAsync(bsize, 0, (size_t)NBUK * PAD * 4, stream);
    bsize_kernel<<<nb_bs, BS_BLK, 0, stream>>>(dst, bsize, E, NBUK);
    scan_kernel<<<1, SC_BLK, 0, stream>>>(bsize, bstart, gcur, NBUK);
    bin_kernel<<<nb_bin, BIN_BLK, 0, stream>>>(src, dst, gcur, ep, E, NBUK);
    dtf1_kernel<<<NBUK, AGG_BLK, 0, stream>>>(ep, bstart, x, W1, dinv, g1, N);
    agg12_kernel<<<NBUK, AGG_BLK, 0, stream>>>(ep, bstart, g1, dinv, b1, W2, g2, N);
    agg23_kernel<<<NBUK, AGG_BLK, 0, stream>>>(ep, bstart, g2, dinv, b2, W3, g3, N);
    agg3f_kernel<<<NBUK, AGG_BLK, 0, stream>>>(ep, bstart, g3, dinv, b3, Wl, bl, out, N);
}